// Round 7
// baseline (193.702 us; speedup 1.0000x reference)
//
#include <hip/hip_runtime.h>
#include <hip/hip_fp16.h>

// Tree NN: reps = emb[tokens] (4096 x 128 x 128); 7x: reps = tanh(concat(pairs) @ W_tree^T + b);
// out = root @ W_cls^T + b_cls.
//
// R7: pin the occupancy target. R5/R6 counters showed VGPR_Count pinned at 84 = 512/6:
// the backend's heuristic targeted 6 waves/EU (unreachable -- LDS 51.2 KB caps at 3
// blocks/CU) and spilled the gather prefetch to scratch to get there (WRITE_SIZE 150.8 MB
// = pf[8] round-tripping per sample). launch_bounds' 2nd arg is only a MINIMUM; the fix is
// __attribute__((amdgpu_waves_per_eu(3,3))) -> allocator budget 170 VGPR, no occupancy
// chasing. Expected demand ~155 (Wf 64 + pf 32 + acc 32 + temps).
//
// Retained from R6: fp16 embedding table pre-pass into d_ws (halves gather bytes, removes
// converts from hot loop); sample s+1's gather prefetched into uint4 pf[8] across the levels.
// Wave w owns output n-tiles {2w,2w+1} at every level (Wf[2][8] = 64 VGPR of W-fragments).
// Activations in LDS, pair-contiguous so concat(left,right) is free.
// fp16 MFMA 16x16x32, fp32 accumulate, fp32 tanh, fp32 classifier.

typedef _Float16 half8 __attribute__((ext_vector_type(8)));
typedef float floatx4 __attribute__((ext_vector_type(4)));

#define STRIDE 264   // 256 + 8 fp16 pad (132 dwords, 33 uint4): A-row ds_read_b128 2-way (free)
#define NSAMP 4096
#define EMB_ELEMS (100000 * 128)

__device__ __forceinline__ float fast_tanh(float x) {
  // No clamp needed: e=inf -> 1-2*rcp(inf)=1; e=0 -> 1-2*rcp(1)=-1. Inputs never NaN.
  float e = __expf(2.f * x);
  return 1.f - 2.f * __builtin_amdgcn_rcpf(e + 1.f);
}

__device__ __forceinline__ unsigned pkrtz(float a, float b) {
  auto h = __builtin_amdgcn_cvt_pkrtz(a, b);   // __fp16 ext_vector(2)
  return __builtin_bit_cast(unsigned, h);
}

// ---- embedding fp32 -> fp16 pre-pass (once per launch; ~77 MB traffic ~ 13 us) ----
__global__ __launch_bounds__(256) void convert_emb(const float* __restrict__ emb,
                                                   _Float16* __restrict__ emb16, int n8) {
  int i = blockIdx.x * 256 + threadIdx.x;      // one thread per 8 elements
  if (i < n8) {
    float4 a = ((const float4*)emb)[2 * i];
    float4 b = ((const float4*)emb)[2 * i + 1];
    uint4 w;
    w.x = pkrtz(a.x, a.y); w.y = pkrtz(a.z, a.w);
    w.z = pkrtz(b.x, b.y); w.w = pkrtz(b.z, b.w);
    ((uint4*)emb16)[i] = w;
  }
}

// One wave computes its 2 n-tiles for MT m-tiles of one level.
// A-frag: A[m=lane&15][k=quad*8+j]; B-frag: B[k=quad*8+j][n=lane&15];
// D: col=lane&15, row=quad*4+reg (verified layouts, learn_hip m89/m91).
template<int MT>
__device__ __forceinline__ void level_run(
    const _Float16* inb, _Float16* outb, float* rootbuf,
    const half8 (&Wf)[2][8], const float (&bias)[2],
    int Mout, bool writeRoot, int nbase, int l15, int quad)
{
  floatx4 acc[MT][2];
#pragma unroll
  for (int m = 0; m < MT; ++m) {
    acc[m][0] = (floatx4){0.f, 0.f, 0.f, 0.f};
    acc[m][1] = (floatx4){0.f, 0.f, 0.f, 0.f};
  }

#pragma unroll
  for (int m = 0; m < MT; ++m) {
    const _Float16* arow = inb + (m * 16 + l15) * STRIDE + quad * 8;
#pragma unroll
    for (int ks = 0; ks < 8; ++ks) {         // K = 256 = 8 steps of 32
      half8 a = *(const half8*)(arow + ks * 32);
      acc[m][0] = __builtin_amdgcn_mfma_f32_16x16x32_f16(a, Wf[0][ks], acc[m][0], 0, 0, 0);
      acc[m][1] = __builtin_amdgcn_mfma_f32_16x16x32_f16(a, Wf[1][ks], acc[m][1], 0, 0, 0);
    }
  }

  const int mrow = quad * 4;
#pragma unroll
  for (int m = 0; m < MT; ++m) {
#pragma unroll
    for (int i = 0; i < 2; ++i) {
      const int col = (nbase + i) * 16 + l15;  // output feature e
      const float b = bias[i];
#pragma unroll
      for (int r = 0; r < 4; ++r) {
        const int node = m * 16 + mrow + r;
        if (node < Mout) {                     // padded rows at deep levels: skip
          float v = fast_tanh(acc[m][i][r] + b);
          if (writeRoot) {
            rootbuf[col] = v;                  // Mout==1: only node 0 lands here, fp32
          } else {
            // pair-contiguous store: node j -> row j>>1, half j&1 (next level's A-matrix)
            outb[(node >> 1) * STRIDE + (node & 1) * 128 + col] = (_Float16)v;
          }
        }
      }
    }
  }
}

template<bool F16>
__global__ __launch_bounds__(256)
__attribute__((amdgpu_waves_per_eu(3, 3)))   // pin: stops allocator chasing 6 waves/EU (R5/R6 spill)
void tree_kernel(const int* __restrict__ tokens,
                 const float* __restrict__ embedding,
                 const _Float16* __restrict__ emb16,
                 const float* __restrict__ W_tree,
                 const float* __restrict__ b_tree,
                 const float* __restrict__ W_cls,
                 const float* __restrict__ b_cls,
                 float* __restrict__ out)
{
  __shared__ _Float16 bufA[64 * STRIDE];   // leaves / even-level outputs (33.8 KB)
  __shared__ _Float16 bufB[32 * STRIDE];   // odd-level outputs (16.9 KB)
  __shared__ float rootbuf[128];

  const int tid  = threadIdx.x;
  const int wid  = tid >> 6;
  const int lane = tid & 63;
  const int l15  = lane & 15;
  const int quad = lane >> 4;
  const int nbase = wid * 2;               // this wave's n-tile base (features [32*wid, 32*wid+32))

  // ---- stage this wave's 2 n-tiles of W_tree into registers as B-fragments ----
  // B[k][n] = W_tree[e=n][h=k]  (einsum 'bnh,eh->bne' => out = comb @ W^T)
  half8 Wf[2][8];                          // 64 VGPRs
#pragma unroll
  for (int i = 0; i < 2; ++i) {
    const int e = (nbase + i) * 16 + l15;
#pragma unroll
    for (int ks = 0; ks < 8; ++ks) {
      const int k = ks * 32 + quad * 8;
      const float4* p = (const float4*)(W_tree + e * 256 + k);
      float4 lo = p[0], hi = p[1];
      half8 f;
      f[0] = (_Float16)lo.x; f[1] = (_Float16)lo.y; f[2] = (_Float16)lo.z; f[3] = (_Float16)lo.w;
      f[4] = (_Float16)hi.x; f[5] = (_Float16)hi.y; f[6] = (_Float16)hi.z; f[7] = (_Float16)hi.w;
      Wf[i][ks] = f;
    }
  }
  float bias[2];
#pragma unroll
  for (int i = 0; i < 2; ++i) bias[i] = b_tree[(nbase + i) * 16 + l15];

  // ---- gather pipeline state: each thread owns half an embedding row ----
  const int leaf = tid >> 1;               // 0..127
  const int hh   = tid & 1;                // which 64-feature half of the row
  uint4 pf[8];                             // fp16 prefetch: 32 VGPRs in flight across levels

  if (F16) {                               // prologue: issue first sample's gather
    const int tok = tokens[blockIdx.x * 128 + leaf];
    const uint4* src = (const uint4*)(emb16 + (size_t)tok * 128 + hh * 64);
#pragma unroll
    for (int j = 0; j < 8; ++j) pf[j] = src[j];
  }

#pragma unroll 1
  for (int s = blockIdx.x; s < NSAMP; s += gridDim.x) {

    uint4* dst = (uint4*)bufA + (leaf >> 1) * 33 + (leaf & 1) * 16 + hh * 8;
    if (F16) {
      // ---- drain prefetch: raw ds_write_b128, pair-contiguous into bufA ----
#pragma unroll
      for (int j = 0; j < 8; ++j) dst[j] = pf[j];
      // ---- issue next sample's gather (lands during this sample's 7 levels) ----
      int snext = s + gridDim.x;
      if (snext >= NSAMP) snext = s;       // harmless re-load on last iteration
      const int tok = tokens[snext * 128 + leaf];
      const uint4* src = (const uint4*)(emb16 + (size_t)tok * 128 + hh * 64);
#pragma unroll
      for (int j = 0; j < 8; ++j) pf[j] = src[j];
    } else {
      // fallback: direct fp32 gather + convert (R3 style, no prefetch)
      const int tok = tokens[s * 128 + leaf];
      const float4* src = (const float4*)(embedding + (size_t)tok * 128 + hh * 64);
#pragma unroll
      for (int j = 0; j < 8; ++j) {
        float4 x = src[2 * j], y = src[2 * j + 1];
        uint4 w;
        w.x = pkrtz(x.x, x.y); w.y = pkrtz(x.z, x.w);
        w.z = pkrtz(y.x, y.y); w.w = pkrtz(y.z, y.w);
        dst[j] = w;
      }
    }
    __syncthreads();

    // ---- 7 tree levels (ping-pong bufA/bufB) ----
    // Mout = 64,32,16,8,4,2,1 ; MT = 4,2,1,1,1,1,1
    level_run<4>(bufA, bufB, rootbuf, Wf, bias, 64, false, nbase, l15, quad);
    __syncthreads();
    level_run<2>(bufB, bufA, rootbuf, Wf, bias, 32, false, nbase, l15, quad);
    __syncthreads();
    level_run<1>(bufA, bufB, rootbuf, Wf, bias, 16, false, nbase, l15, quad);
    __syncthreads();
    level_run<1>(bufB, bufA, rootbuf, Wf, bias,  8, false, nbase, l15, quad);
    __syncthreads();
    level_run<1>(bufA, bufB, rootbuf, Wf, bias,  4, false, nbase, l15, quad);
    __syncthreads();
    level_run<1>(bufB, bufA, rootbuf, Wf, bias,  2, false, nbase, l15, quad);
    __syncthreads();
    level_run<1>(bufA, bufB, rootbuf, Wf, bias,  1, true,  nbase, l15, quad);
    __syncthreads();

    // ---- classifier: wave 0, fp32, shuffle reduction ----
    if (wid == 0) {
      const float r0 = rootbuf[lane];
      const float r1 = rootbuf[lane + 64];
#pragma unroll
      for (int o = 0; o < 3; ++o) {
        float p = r0 * W_cls[o * 128 + lane] + r1 * W_cls[o * 128 + 64 + lane];
#pragma unroll
        for (int sh = 32; sh > 0; sh >>= 1) p += __shfl_down(p, sh, 64);
        if (lane == 0) out[s * 3 + o] = p + b_cls[o];
      }
    }
    // next iteration's ds_write to bufA is safe: last bufA reader (root level) is behind
    // the final barrier. classifier reads rootbuf, next written 7 barriers later.
  }
}

extern "C" void kernel_launch(void* const* d_in, const int* in_sizes, int n_in,
                              void* d_out, int out_size, void* d_ws, size_t ws_size,
                              hipStream_t stream) {
  const int*   tokens    = (const int*)d_in[0];
  const float* embedding = (const float*)d_in[1];
  const float* W_tree    = (const float*)d_in[2];
  const float* b_tree    = (const float*)d_in[3];
  const float* W_cls     = (const float*)d_in[4];
  const float* b_cls     = (const float*)d_in[5];
  float* out = (float*)d_out;

  const size_t need = (size_t)EMB_ELEMS * sizeof(_Float16);  // 25.6 MB
  if (ws_size >= need) {
    _Float16* emb16 = (_Float16*)d_ws;
    const int n8 = EMB_ELEMS / 8;                            // 1.6M
    convert_emb<<<dim3((n8 + 255) / 256), dim3(256), 0, stream>>>(embedding, emb16, n8);
    tree_kernel<true><<<dim3(768), dim3(256), 0, stream>>>(
        tokens, embedding, emb16, W_tree, b_tree, W_cls, b_cls, out);
  } else {
    tree_kernel<false><<<dim3(768), dim3(256), 0, stream>>>(
        tokens, embedding, nullptr, W_tree, b_tree, W_cls, b_cls, out);
  }
}

// Round 8
// 164.016 us; speedup vs baseline: 1.1810x; 1.1810x over previous
//
#include <hip/hip_runtime.h>
#include <hip/hip_fp16.h>

// Tree NN: reps = emb[tokens] (4096 x 128 x 128); 7x: reps = tanh(concat(pairs) @ W_tree^T + b);
// out = root @ W_cls^T + b_cls.
//
// R8: consolidation. R5-R7 lessons:
//  (a) register prefetch across the level loop ALWAYS spills (allocator pins ~80-84 VGPR
//      for a 6-waves/EU target; launch_bounds(256,3) and amdgpu_waves_per_eu(3,3) both
//      failed to lift it) AND is structurally useless: __syncthreads drains vmcnt(0), so
//      prefetched loads are force-completed at the first of 8 barriers anyway.
//  (b) the fp16-table pre-pass (~14us/call) costs more than it saves on the scored bench
//      (R3 bench 182 < R6 189 despite worse dispatch). Dropped.
// Kept from R3 (proven no-spill: VGPR 80, WRITE 0.17MB): fp32 direct gather, 768 blocks,
// launch_bounds(256,3). New: pkrtz packed converts in gather; K-split (2 independent
// 4-deep MFMA chains) in the MT=1 deep levels to halve their dependency critical path;
// static MOUT template for epilogue predication.
//
// Wave w owns output n-tiles {2w,2w+1} at every level (Wf[2][8] = 64 VGPR of W-fragments).
// Activations in LDS, pair-contiguous so concat(left,right) is free.
// fp16 MFMA 16x16x32, fp32 accumulate, fp32 tanh, fp32 classifier.

typedef _Float16 half8 __attribute__((ext_vector_type(8)));
typedef float floatx4 __attribute__((ext_vector_type(4)));

#define STRIDE 264   // 256 + 8 fp16 pad (33 uint4 chunks/row): A-row ds_read_b128 2-way (free)
#define NSAMP 4096

__device__ __forceinline__ float fast_tanh(float x) {
  // No clamp needed: e=inf -> 1-2*rcp(inf)=1; e=0 -> 1-2*rcp(1)=-1. Inputs never NaN.
  float e = __expf(2.f * x);
  return 1.f - 2.f * __builtin_amdgcn_rcpf(e + 1.f);
}

__device__ __forceinline__ unsigned pkrtz(float a, float b) {
  auto h = __builtin_amdgcn_cvt_pkrtz(a, b);   // __fp16 ext_vector(2)
  return __builtin_bit_cast(unsigned, h);
}

// One wave computes its 2 n-tiles for MT m-tiles of one level.
// A-frag: A[m=lane&15][k=quad*8+j]; B-frag: B[k=quad*8+j][n=lane&15];
// D: col=lane&15, row=quad*4+reg (verified layouts, learn_hip m89/m91).
template<int MT, int MOUT, bool ROOT>
__device__ __forceinline__ void level_run(
    const _Float16* inb, _Float16* outb, float* rootbuf,
    const half8 (&Wf)[2][8], const float (&bias)[2],
    int nbase, int l15, int quad)
{
  floatx4 acc[MT][2];

  if (MT == 1) {
    // Deep level: K-split into two independent 4-deep MFMA chains per n-tile (R8).
    floatx4 accB[2];
    acc[0][0] = (floatx4){0.f, 0.f, 0.f, 0.f};
    acc[0][1] = (floatx4){0.f, 0.f, 0.f, 0.f};
    accB[0]   = (floatx4){0.f, 0.f, 0.f, 0.f};
    accB[1]   = (floatx4){0.f, 0.f, 0.f, 0.f};
    const _Float16* arow = inb + l15 * STRIDE + quad * 8;
#pragma unroll
    for (int ks = 0; ks < 4; ++ks) {
      half8 a0 = *(const half8*)(arow + ks * 32);
      half8 a1 = *(const half8*)(arow + (ks + 4) * 32);
      acc[0][0] = __builtin_amdgcn_mfma_f32_16x16x32_f16(a0, Wf[0][ks],     acc[0][0], 0, 0, 0);
      accB[0]   = __builtin_amdgcn_mfma_f32_16x16x32_f16(a1, Wf[0][ks + 4], accB[0],   0, 0, 0);
      acc[0][1] = __builtin_amdgcn_mfma_f32_16x16x32_f16(a0, Wf[1][ks],     acc[0][1], 0, 0, 0);
      accB[1]   = __builtin_amdgcn_mfma_f32_16x16x32_f16(a1, Wf[1][ks + 4], accB[1],   0, 0, 0);
    }
    acc[0][0] += accB[0];
    acc[0][1] += accB[1];
  } else {
#pragma unroll
    for (int m = 0; m < MT; ++m) {
      acc[m][0] = (floatx4){0.f, 0.f, 0.f, 0.f};
      acc[m][1] = (floatx4){0.f, 0.f, 0.f, 0.f};
    }
#pragma unroll
    for (int m = 0; m < MT; ++m) {
      const _Float16* arow = inb + (m * 16 + l15) * STRIDE + quad * 8;
#pragma unroll
      for (int ks = 0; ks < 8; ++ks) {       // K = 256 = 8 steps of 32
        half8 a = *(const half8*)(arow + ks * 32);
        acc[m][0] = __builtin_amdgcn_mfma_f32_16x16x32_f16(a, Wf[0][ks], acc[m][0], 0, 0, 0);
        acc[m][1] = __builtin_amdgcn_mfma_f32_16x16x32_f16(a, Wf[1][ks], acc[m][1], 0, 0, 0);
      }
    }
  }

  const int mrow = quad * 4;
#pragma unroll
  for (int m = 0; m < MT; ++m) {
#pragma unroll
    for (int i = 0; i < 2; ++i) {
      const int col = (nbase + i) * 16 + l15;  // output feature e
      const float b = bias[i];
#pragma unroll
      for (int r = 0; r < 4; ++r) {
        const int node = m * 16 + mrow + r;
        if (node < MOUT) {                     // constant-folds per (m,r,quad) at deep levels
          float v = fast_tanh(acc[m][i][r] + b);
          if (ROOT) {
            rootbuf[col] = v;                  // MOUT==1: only node 0 lands here, fp32
          } else {
            // pair-contiguous store: node j -> row j>>1, half j&1 (next level's A-matrix)
            outb[(node >> 1) * STRIDE + (node & 1) * 128 + col] = (_Float16)v;
          }
        }
      }
    }
  }
}

__global__ __launch_bounds__(256, 3)
void tree_kernel(const int* __restrict__ tokens,
                 const float* __restrict__ embedding,
                 const float* __restrict__ W_tree,
                 const float* __restrict__ b_tree,
                 const float* __restrict__ W_cls,
                 const float* __restrict__ b_cls,
                 float* __restrict__ out)
{
  __shared__ __align__(16) _Float16 bufA[64 * STRIDE];   // leaves / even outputs (33.8 KB)
  __shared__ __align__(16) _Float16 bufB[32 * STRIDE];   // odd outputs (16.9 KB)
  __shared__ float rootbuf[128];

  const int tid  = threadIdx.x;
  const int wid  = tid >> 6;
  const int lane = tid & 63;
  const int l15  = lane & 15;
  const int quad = lane >> 4;
  const int nbase = wid * 2;               // this wave's n-tile base (features [32*wid, 32*wid+32))

  // ---- stage this wave's 2 n-tiles of W_tree into registers as B-fragments ----
  // B[k][n] = W_tree[e=n][h=k]  (einsum 'bnh,eh->bne' => out = comb @ W^T)
  half8 Wf[2][8];                          // 64 VGPRs
#pragma unroll
  for (int i = 0; i < 2; ++i) {
    const int e = (nbase + i) * 16 + l15;
#pragma unroll
    for (int ks = 0; ks < 8; ++ks) {
      const int k = ks * 32 + quad * 8;
      const float4* p = (const float4*)(W_tree + e * 256 + k);
      float4 lo = p[0], hi = p[1];
      half8 f;
      f[0] = (_Float16)lo.x; f[1] = (_Float16)lo.y; f[2] = (_Float16)lo.z; f[3] = (_Float16)lo.w;
      f[4] = (_Float16)hi.x; f[5] = (_Float16)hi.y; f[6] = (_Float16)hi.z; f[7] = (_Float16)hi.w;
      Wf[i][ks] = f;
    }
  }
  float bias[2];
#pragma unroll
  for (int i = 0; i < 2; ++i) bias[i] = b_tree[(nbase + i) * 16 + l15];

  const int leaf = tid >> 1;               // 0..127
  const int hh   = tid & 1;                // which 64-feature half of the row

#pragma unroll 1
  for (int s = blockIdx.x; s < NSAMP; s += gridDim.x) {

    // ---- gather: 128 leaves x 128 feats, fp32 -> fp16 (pkrtz), pair-contiguous in bufA ----
    {
      const int tok = tokens[s * 128 + leaf];
      const float4* src = (const float4*)(embedding + (size_t)tok * 128 + hh * 64);
      uint4* dst = (uint4*)bufA + (leaf >> 1) * 33 + (leaf & 1) * 16 + hh * 8;
#pragma unroll
      for (int j = 0; j < 8; ++j) {
        float4 x = src[2 * j], y = src[2 * j + 1];
        uint4 w;
        w.x = pkrtz(x.x, x.y); w.y = pkrtz(x.z, x.w);
        w.z = pkrtz(y.x, y.y); w.w = pkrtz(y.z, y.w);
        dst[j] = w;                        // ds_write_b128, 16B aligned
      }
    }
    __syncthreads();

    // ---- 7 tree levels (ping-pong bufA/bufB) ----
    // MOUT = 64,32,16,8,4,2,1 ; MT = 4,2,1,1,1,1,1
    level_run<4, 64, false>(bufA, bufB, rootbuf, Wf, bias, nbase, l15, quad);
    __syncthreads();
    level_run<2, 32, false>(bufB, bufA, rootbuf, Wf, bias, nbase, l15, quad);
    __syncthreads();
    level_run<1, 16, false>(bufA, bufB, rootbuf, Wf, bias, nbase, l15, quad);
    __syncthreads();
    level_run<1,  8, false>(bufB, bufA, rootbuf, Wf, bias, nbase, l15, quad);
    __syncthreads();
    level_run<1,  4, false>(bufA, bufB, rootbuf, Wf, bias, nbase, l15, quad);
    __syncthreads();
    level_run<1,  2, false>(bufB, bufA, rootbuf, Wf, bias, nbase, l15, quad);
    __syncthreads();
    level_run<1,  1, true >(bufA, bufB, rootbuf, Wf, bias, nbase, l15, quad);
    __syncthreads();

    // ---- classifier: wave 0, fp32, shuffle reduction ----
    if (wid == 0) {
      const float r0 = rootbuf[lane];
      const float r1 = rootbuf[lane + 64];
#pragma unroll
      for (int o = 0; o < 3; ++o) {
        float p = r0 * W_cls[o * 128 + lane] + r1 * W_cls[o * 128 + 64 + lane];
#pragma unroll
        for (int sh = 32; sh > 0; sh >>= 1) p += __shfl_down(p, sh, 64);
        if (lane == 0) out[s * 3 + o] = p + b_cls[o];
      }
    }
    // next iteration's ds_write to bufA is safe: last bufA reader (root level) is behind
    // the final barrier. classifier reads rootbuf, next written 7 barriers later.
  }
}

extern "C" void kernel_launch(void* const* d_in, const int* in_sizes, int n_in,
                              void* d_out, int out_size, void* d_ws, size_t ws_size,
                              hipStream_t stream) {
  const int*   tokens    = (const int*)d_in[0];
  const float* embedding = (const float*)d_in[1];
  const float* W_tree    = (const float*)d_in[2];
  const float* b_tree    = (const float*)d_in[3];
  const float* W_cls     = (const float*)d_in[4];
  const float* b_cls     = (const float*)d_in[5];
  float* out = (float*)d_out;

  dim3 grid(768), block(256);   // 3 blocks/CU x 256 CUs; grid-stride over 4096 samples
  tree_kernel<<<grid, block, 0, stream>>>(tokens, embedding, W_tree, b_tree, W_cls, b_cls, out);
}

// Round 9
// 156.835 us; speedup vs baseline: 1.2351x; 1.0458x over previous
//
#include <hip/hip_runtime.h>
#include <hip/hip_fp16.h>

// Tree NN: reps = emb[tokens] (4096 x 128 x 128); 7x: reps = tanh(concat(pairs) @ W_tree^T + b);
// out = root @ W_cls^T + b_cls.
//
// R9: pair-batch the deep tail. R8 counters (MfmaUtil 21, VALU 31, HBM 17%, occ 28.5%) are
// still latency-bound: 8 barrier-separated stages/sample, and L4-L6 tiles are mostly
// garbage rows. Samples now processed in pairs: phase-1 (gather..L4) per sample, L4 output
// (2 rows/sample) stashed in bufC (4 rows, 2.1 KB; total LDS 52896 <= 54272 = 3-blocks/CU
// limit); L5+L6 run ONCE for both samples (full tiles). Classifier from registers:
// W_cls hoisted per-lane, wave shuffle partials, tiny LDS combine (rootbuf removed).
// Barriers 16->14/pair, MFMA 352->320/wave/pair, deep epilogue halved.
// bufC reads row-clamped (min(l15,3)) to stay in-bounds; garbage rows masked at store.
//
// Wave w owns output n-tiles {2w,2w+1} at every level (Wf[2][8] = 64 VGPR of W-fragments).
// Activations in LDS, pair-contiguous so concat(left,right) is free.
// fp16 MFMA 16x16x32 (K-split: 2 independent 4-chains), fp32 accumulate/tanh/classifier.

typedef _Float16 half8 __attribute__((ext_vector_type(8)));
typedef float floatx4 __attribute__((ext_vector_type(4)));

#define STRIDE 264   // 256 + 8 fp16 pad: A-row ds_read_b128 conflict-free
#define NPAIR 2048

__device__ __forceinline__ float fast_tanh(float x) {
  // No clamp needed: e=inf -> 1-2*rcp(inf)=1; e=0 -> -1. Inputs never NaN.
  float e = __expf(2.f * x);
  return 1.f - 2.f * __builtin_amdgcn_rcpf(e + 1.f);
}

__device__ __forceinline__ unsigned pkrtz(float a, float b) {
  auto h = __builtin_amdgcn_cvt_pkrtz(a, b);   // __fp16 ext_vector(2)
  return __builtin_bit_cast(unsigned, h);
}

// K=256 MFMA for one 16-row m-tile, 2 n-tiles, K-split into 2 independent 4-chains.
// A-frag: A[m=lane&15][k=quad*8+j]; B-frag: B[k=quad*8+j][n=lane&15];
// D: col=lane&15, row=quad*4+reg (verified layouts, learn_hip m89/m91).
__device__ __forceinline__ void mfma_k256(const _Float16* arow, const half8 (&Wf)[2][8],
                                          floatx4 (&accO)[2]) {
  floatx4 aA[2], aB[2];
  aA[0] = (floatx4){0.f, 0.f, 0.f, 0.f}; aA[1] = (floatx4){0.f, 0.f, 0.f, 0.f};
  aB[0] = (floatx4){0.f, 0.f, 0.f, 0.f}; aB[1] = (floatx4){0.f, 0.f, 0.f, 0.f};
#pragma unroll
  for (int ks = 0; ks < 4; ++ks) {
    half8 x0 = *(const half8*)(arow + ks * 32);
    half8 x1 = *(const half8*)(arow + (ks + 4) * 32);
    aA[0] = __builtin_amdgcn_mfma_f32_16x16x32_f16(x0, Wf[0][ks],     aA[0], 0, 0, 0);
    aB[0] = __builtin_amdgcn_mfma_f32_16x16x32_f16(x1, Wf[0][ks + 4], aB[0], 0, 0, 0);
    aA[1] = __builtin_amdgcn_mfma_f32_16x16x32_f16(x0, Wf[1][ks],     aA[1], 0, 0, 0);
    aB[1] = __builtin_amdgcn_mfma_f32_16x16x32_f16(x1, Wf[1][ks + 4], aB[1], 0, 0, 0);
  }
  accO[0] = aA[0] + aB[0];
  accO[1] = aA[1] + aB[1];
}

// One wave: its 2 n-tiles for MT m-tiles; standard pair-contiguous store, MOUT row mask.
template<int MT, int MOUT>
__device__ __forceinline__ void level_std(
    const _Float16* inb, _Float16* outb,
    const half8 (&Wf)[2][8], const float (&bias)[2],
    int nbase, int l15, int quad)
{
  floatx4 acc[MT][2];
  if (MT == 1) {
    floatx4 a2[2];
    mfma_k256(inb + l15 * STRIDE + quad * 8, Wf, a2);
    acc[0][0] = a2[0]; acc[0][1] = a2[1];
  } else {
#pragma unroll
    for (int m = 0; m < MT; ++m) {
      acc[m][0] = (floatx4){0.f, 0.f, 0.f, 0.f};
      acc[m][1] = (floatx4){0.f, 0.f, 0.f, 0.f};
    }
#pragma unroll
    for (int m = 0; m < MT; ++m) {
      const _Float16* arow = inb + (m * 16 + l15) * STRIDE + quad * 8;
#pragma unroll
      for (int ks = 0; ks < 8; ++ks) {
        half8 a = *(const half8*)(arow + ks * 32);
        acc[m][0] = __builtin_amdgcn_mfma_f32_16x16x32_f16(a, Wf[0][ks], acc[m][0], 0, 0, 0);
        acc[m][1] = __builtin_amdgcn_mfma_f32_16x16x32_f16(a, Wf[1][ks], acc[m][1], 0, 0, 0);
      }
    }
  }

  const int mrow = quad * 4;
#pragma unroll
  for (int m = 0; m < MT; ++m) {
#pragma unroll
    for (int i = 0; i < 2; ++i) {
      const int col = (nbase + i) * 16 + l15;
      const float b = bias[i];
#pragma unroll
      for (int r = 0; r < 4; ++r) {
        const int node = m * 16 + mrow + r;
        if (node < MOUT) {
          float v = fast_tanh(acc[m][i][r] + b);
          outb[(node >> 1) * STRIDE + (node & 1) * 128 + col] = (_Float16)v;
        }
      }
    }
  }
}

__global__ __launch_bounds__(256, 3)
void tree_kernel(const int* __restrict__ tokens,
                 const float* __restrict__ embedding,
                 const float* __restrict__ W_tree,
                 const float* __restrict__ b_tree,
                 const float* __restrict__ W_cls,
                 const float* __restrict__ b_cls,
                 float* __restrict__ out)
{
  __shared__ __align__(16) _Float16 bufA[64 * STRIDE];   // leaves / even outputs (33.8 KB)
  __shared__ __align__(16) _Float16 bufB[32 * STRIDE];   // odd outputs (16.9 KB)
  __shared__ __align__(16) _Float16 bufC[4 * STRIDE];    // pair stash: L4 outs (2.1 KB)
  __shared__ float wavepart[4][2][3];                    // classifier partials (96 B)

  const int tid  = threadIdx.x;
  const int wid  = tid >> 6;
  const int lane = tid & 63;
  const int l15  = lane & 15;
  const int quad = lane >> 4;
  const int nbase = wid * 2;               // this wave's n-tile base (features [32*wid,32*wid+32))

  // ---- stage this wave's 2 n-tiles of W_tree as B-fragments (64 VGPR) ----
  // B[k][n] = W_tree[e=n][h=k]  (einsum 'bnh,eh->bne' => out = comb @ W^T)
  half8 Wf[2][8];
#pragma unroll
  for (int i = 0; i < 2; ++i) {
    const int e = (nbase + i) * 16 + l15;
#pragma unroll
    for (int ks = 0; ks < 8; ++ks) {
      const int k = ks * 32 + quad * 8;
      const float4* p = (const float4*)(W_tree + e * 256 + k);
      float4 lo = p[0], hi = p[1];
      half8 f;
      f[0] = (_Float16)lo.x; f[1] = (_Float16)lo.y; f[2] = (_Float16)lo.z; f[3] = (_Float16)lo.w;
      f[4] = (_Float16)hi.x; f[5] = (_Float16)hi.y; f[6] = (_Float16)hi.z; f[7] = (_Float16)hi.w;
      Wf[i][ks] = f;
    }
  }
  float bias[2];
#pragma unroll
  for (int i = 0; i < 2; ++i) bias[i] = b_tree[(nbase + i) * 16 + l15];

  // classifier weights for this lane's 2 columns: loop-invariant (6 VGPR)
  float wc[2][3];
#pragma unroll
  for (int i = 0; i < 2; ++i) {
    const int col = (nbase + i) * 16 + l15;
#pragma unroll
    for (int o = 0; o < 3; ++o) wc[i][o] = W_cls[o * 128 + col];
  }

  const int leaf = tid >> 1;               // 0..127
  const int hh   = tid & 1;                // which 64-feature half of the row

#pragma unroll 1
  for (int p = blockIdx.x; p < NPAIR; p += gridDim.x) {

    // ---- phase 1 per sample: gather + L0..L4, stash L4-out into bufC rows [2j,2j+2) ----
#pragma unroll 1
    for (int j = 0; j < 2; ++j) {
      const int s = 2 * p + j;
      {
        const int tok = tokens[s * 128 + leaf];
        const float4* src = (const float4*)(embedding + (size_t)tok * 128 + hh * 64);
        uint4* dst = (uint4*)bufA + (leaf >> 1) * 33 + (leaf & 1) * 16 + hh * 8;
#pragma unroll
        for (int jj = 0; jj < 8; ++jj) {
          float4 x = src[2 * jj], y = src[2 * jj + 1];
          uint4 w;
          w.x = pkrtz(x.x, x.y); w.y = pkrtz(x.z, x.w);
          w.z = pkrtz(y.x, y.y); w.w = pkrtz(y.z, y.w);
          dst[jj] = w;
        }
      }
      __syncthreads();
      level_std<4, 64>(bufA, bufB, Wf, bias, nbase, l15, quad);   // L0
      __syncthreads();
      level_std<2, 32>(bufB, bufA, Wf, bias, nbase, l15, quad);   // L1
      __syncthreads();
      level_std<1, 16>(bufA, bufB, Wf, bias, nbase, l15, quad);   // L2
      __syncthreads();
      level_std<1,  8>(bufB, bufA, Wf, bias, nbase, l15, quad);   // L3 (rows 8-15 garbage, masked)
      __syncthreads();
      level_std<1,  4>(bufA, bufC + j * 2 * STRIDE,               // L4 -> stash
                       Wf, bias, nbase, l15, quad);
      __syncthreads();
    }

    // ---- batched L5: bufC 4 rows (sample j at rows 2j..2j+2) -> bufA rows 0-1 ----
    // node enumeration across the pair IS the standard pair-contig mapping (node=mr).
    {
      const int rclamp = l15 < 4 ? l15 : 3;          // stay in bufC bounds; rows>=4 discarded
      floatx4 acc[2];
      mfma_k256(bufC + rclamp * STRIDE + quad * 8, Wf, acc);
      const int mrow = quad * 4;
#pragma unroll
      for (int i = 0; i < 2; ++i) {
        const int col = (nbase + i) * 16 + l15;
#pragma unroll
        for (int r = 0; r < 4; ++r) {
          const int mr = mrow + r;                   // mr<4 valid: sample mr>>1, node mr&1
          if (mr < 4) {
            float v = fast_tanh(acc[i][r] + bias[i]);
            bufA[(mr >> 1) * STRIDE + (mr & 1) * 128 + col] = (_Float16)v;
          }
        }
      }
    }
    __syncthreads();

    // ---- batched L6 + classifier partials from registers ----
    {
      floatx4 acc[2];
      mfma_k256(bufA + l15 * STRIDE + quad * 8, Wf, acc);  // rows 0-1 valid = roots of s0,s1
      float part[2][3] = {{0.f, 0.f, 0.f}, {0.f, 0.f, 0.f}};
      if (quad == 0) {
#pragma unroll
        for (int i = 0; i < 2; ++i) {
#pragma unroll
          for (int rr = 0; rr < 2; ++rr) {           // rr = sample
            float v = fast_tanh(acc[i][rr] + bias[i]);
#pragma unroll
            for (int o = 0; o < 3; ++o) part[rr][o] = fmaf(v, wc[i][o], part[rr][o]);
          }
        }
      }
#pragma unroll
      for (int rr = 0; rr < 2; ++rr) {
#pragma unroll
        for (int o = 0; o < 3; ++o) {
          float v = part[rr][o];                     // nonzero only in quad-0 lanes
          v += __shfl_down(v, 8);
          v += __shfl_down(v, 4);
          v += __shfl_down(v, 2);
          v += __shfl_down(v, 1);
          if (lane == 0) wavepart[wid][rr][o] = v;
        }
      }
    }
    __syncthreads();
    if (tid < 6) {
      const int rr = tid / 3, o = tid - 3 * rr;
      float v = wavepart[0][rr][o] + wavepart[1][rr][o]
              + wavepart[2][rr][o] + wavepart[3][rr][o];
      out[(2 * p + rr) * 3 + o] = v + b_cls[o];
    }
    // next pair's gather writes bufA: all waves' L6 bufA reads completed before the
    // wavepart barrier. wavepart reread only at next pair's L6 (13 barriers away).
  }
}

extern "C" void kernel_launch(void* const* d_in, const int* in_sizes, int n_in,
                              void* d_out, int out_size, void* d_ws, size_t ws_size,
                              hipStream_t stream) {
  const int*   tokens    = (const int*)d_in[0];
  const float* embedding = (const float*)d_in[1];
  const float* W_tree    = (const float*)d_in[2];
  const float* b_tree    = (const float*)d_in[3];
  const float* W_cls     = (const float*)d_in[4];
  const float* b_cls     = (const float*)d_in[5];
  float* out = (float*)d_out;

  dim3 grid(768), block(256);   // 3 blocks/CU x 256 CUs; grid-stride over 2048 pairs
  tree_kernel<<<grid, block, 0, stream>>>(tokens, embedding, W_tree, b_tree, W_cls, b_cls, out);
}